// Round 6
// baseline (397.027 us; speedup 1.0000x reference)
//
#include <hip/hip_runtime.h>
#include <math.h>

// Heat equation, temporally blocked, K=16 steps/launch, 16 dispatches.
// Round 5: TWO blocks per CU to break the barrier convoy. 512 blocks x 512
// threads; core 32x64, tile 64x96 (halo 16), LDS row stride 100, double
// buffered = 51.2 KB/block -> 2 blocks/CU (102.4 of 160 KB). One block's
// per-step barrier stall is hidden by the other block's compute/stores.
// Barriers drain lgkmcnt only; global frame stores stay in flight.

#define CROWS 32
#define CCOLS 64
#define HALO  16
#define TROWS 64           // CROWS + 2*HALO
#define TCOLS 96           // CCOLS + 2*HALO
#define PAD   100          // padded LDS row stride (floats)
#define TPB   512
#define NQ    24           // float4 quads per tile row
#define NIT   (62 * NQ)    // 1488 interior quads per step

__device__ __forceinline__ void slot_init(int it, int o_r, int o_c, int nX,
                                          int& a, size_t& so, bool& st, float4& m) {
    const int r = 1 + it / NQ;
    const int q = it % NQ;
    a = r * PAD + 4 * q;
    const int gr  = o_r + r;
    const int gc0 = o_c + 4 * q;
    so = (size_t)gr * nX + gc0;
    st = (r >= HALO && r < HALO + CROWS && q >= HALO / 4 && q < (TCOLS - HALO) / 4);
    const bool rin = (gr > 0 && gr < nX - 1);
    m.x = (rin && gc0     > 0 && gc0     < nX - 1) ? 1.f : 0.f;
    m.y = (rin && gc0 + 1 > 0 && gc0 + 1 < nX - 1) ? 1.f : 0.f;
    m.z = (rin && gc0 + 2 > 0 && gc0 + 2 < nX - 1) ? 1.f : 0.f;
    m.w = (rin && gc0 + 3 > 0 && gc0 + 3 < nX - 1) ? 1.f : 0.f;
}

__device__ __forceinline__ void step_one(const float* __restrict__ bc,
                                         float* __restrict__ bn,
                                         float* __restrict__ of,
                                         int a, size_t so, bool st,
                                         const float4& m, float4& c, float gamma) {
    const float4 u4 = *reinterpret_cast<const float4*>(bc + a - PAD);
    const float4 d4 = *reinterpret_cast<const float4*>(bc + a + PAD);
    const float lf = bc[a - 1];
    const float rt = bc[a + 4];
    float4 o;
    o.x = m.x * (c.x + gamma * (u4.x + d4.x + lf  + c.y - 4.f * c.x));
    o.y = m.y * (c.y + gamma * (u4.y + d4.y + c.x + c.z - 4.f * c.y));
    o.z = m.z * (c.z + gamma * (u4.z + d4.z + c.y + c.w - 4.f * c.z));
    o.w = m.w * (c.w + gamma * (u4.w + d4.w + c.z + rt  - 4.f * c.w));
    *reinterpret_cast<float4*>(bn + a) = o;
    if (st) *reinterpret_cast<float4*>(of + so) = o;
    c = o;   // this step's output is next step's center
}

__global__ __launch_bounds__(TPB, 4)
void heat_fused(const float* __restrict__ src,       // u0 (first) or frame t_base
                float* __restrict__ out,             // full output base
                int t_base, int k, int nX, int first,
                int time_steps,
                const float* __restrict__ alpha_p,
                const int* __restrict__ T_p) {
    __shared__ float buf[2][TROWS * PAD];

    const int tid = threadIdx.x;
    const int gbx = nX / CCOLS;                // 16 column tiles
    const int bx  = blockIdx.x % gbx;
    const int by  = blockIdx.x / gbx;          // 32 row tiles
    const int o_r = by * CROWS - HALO;
    const int o_c = bx * CCOLS - HALO;

    const float alpha = *alpha_p;
    const float Tf    = (float)(*T_p);
    const float dx    = 6.0f / (float)(nX - 1);
    const float dt    = Tf / (float)(time_steps - 1);
    const float gamma = alpha * dt / (dx * dx);

    // ---- load 64x96 tile (strict interior mask: boundaries/OOD -> 0).
    // For first==1 this mask also produces reference frame 0 from u0.
    for (int idx = tid; idx < TROWS * PAD; idx += TPB) {
        const int r = idx / PAD, c = idx % PAD;
        const int gr = o_r + r, gc = o_c + c;
        float v = 0.f;
        if (c < TCOLS && gr > 0 && gr < nX - 1 && gc > 0 && gc < nX - 1)
            v = src[(size_t)gr * nX + gc];
        buf[0][idx] = v;
        if (first && r >= HALO && r < HALO + CROWS && c >= HALO && c < HALO + CCOLS)
            out[(size_t)gr * nX + gc] = v;           // frame 0
    }
    asm volatile("s_waitcnt lgkmcnt(0)" ::: "memory");
    __builtin_amdgcn_s_barrier();
    __builtin_amdgcn_sched_barrier(0);

    // ---- per-slot loop invariants (3 slots: tid, tid+512, tid+1024) ----
    int a0, a1, a2 = PAD; size_t so0, so1, so2 = 0; bool st0, st1, st2 = false;
    float4 m0, m1, m2 = make_float4(0.f, 0.f, 0.f, 0.f);
    slot_init(tid,       o_r, o_c, nX, a0, so0, st0, m0);
    slot_init(tid + TPB, o_r, o_c, nX, a1, so1, st1, m1);
    const bool has2 = (tid + 2 * TPB) < NIT;
    if (has2) slot_init(tid + 2 * TPB, o_r, o_c, nX, a2, so2, st2, m2);

    float4 c0 = *reinterpret_cast<const float4*>(&buf[0][a0]);
    float4 c1 = *reinterpret_cast<const float4*>(&buf[0][a1]);
    float4 c2 = make_float4(0.f, 0.f, 0.f, 0.f);
    if (has2) c2 = *reinterpret_cast<const float4*>(&buf[0][a2]);

    int cur = 0;
    for (int s = 0; s < k; ++s) {
        const float* __restrict__ bc = buf[cur];
        float*       __restrict__ bn = buf[cur ^ 1];
        float* of = out + (size_t)(t_base + s + 1) * nX * nX;

        step_one(bc, bn, of, a0, so0, st0, m0, c0, gamma);
        step_one(bc, bn, of, a1, so1, st1, m1, c1, gamma);
        if (has2) step_one(bc, bn, of, a2, so2, st2, m2, c2, gamma);

        // LDS-only drain; global stores remain in flight across the barrier
        asm volatile("s_waitcnt lgkmcnt(0)" ::: "memory");
        __builtin_amdgcn_s_barrier();
        __builtin_amdgcn_sched_barrier(0);
        cur ^= 1;
    }
}

extern "C" void kernel_launch(void* const* d_in, const int* in_sizes, int n_in,
                              void* d_out, int out_size, void* d_ws, size_t ws_size,
                              hipStream_t stream) {
    const float* u0      = (const float*)d_in[0];
    const float* alpha_p = (const float*)d_in[1];
    const int*   T_p     = (const int*)d_in[2];

    const int n0 = in_sizes[0];                   // nX*nX
    const int nX = (int)(sqrtf((float)n0) + 0.5f);
    const int ts = out_size / n0;                 // time_steps

    float* out = (float*)d_out;
    const int nblocks = (nX / CCOLS) * (nX / CROWS);   // 16*32 = 512

    for (int t = 0; t < ts - 1; t += HALO) {
        const int k = min(HALO, ts - 1 - t);
        const float* src = (t == 0) ? u0 : out + (size_t)t * n0;
        heat_fused<<<nblocks, TPB, 0, stream>>>(src, out, t, k, nX,
                                                (t == 0) ? 1 : 0, ts,
                                                alpha_p, T_p);
    }
}

// Round 7
// 352.859 us; speedup vs baseline: 1.1252x; 1.1252x over previous
//
#include <hip/hip_runtime.h>
#include <math.h>

// Heat equation, temporally blocked, K=16 steps/launch, 16 dispatches.
// Round 6: producer/consumer wave split inside each 1024-thread block.
//   waves 0-11 (768 thr): LDS stencil only (no global stores)
//   waves 12-15 (256 thr): stream finished frames LDS->global, one step
//     behind compute; both roles only READ the shared buffer, barrier
//     provides ordering. Store backpressure lands on writer waves only.
// Geometry = round-4 best: 64x64 core + 16 halo -> 96x96 tile, PAD=100,
// double buffered (76.8 KB), barriers drain lgkmcnt only.

#define CORE 64
#define HALO 16
#define REG  96            // CORE + 2*HALO
#define PAD  100           // padded LDS row stride (floats)
#define TPB  1024
#define NCT  768           // compute threads (12 waves)
#define NQ   24            // quads per tile row
#define NIT  (94 * NQ)     // 2256 interior quads per step

__device__ __forceinline__ void slot_init(int it, int o_r, int o_c, int nX,
                                          int& a, float4& m) {
    const int r = 1 + it / NQ;
    const int q = it % NQ;
    a = r * PAD + 4 * q;
    const int gr  = o_r + r;
    const int gc0 = o_c + 4 * q;
    const bool rin = (gr > 0 && gr < nX - 1);
    m.x = (rin && gc0     > 0 && gc0     < nX - 1) ? 1.f : 0.f;
    m.y = (rin && gc0 + 1 > 0 && gc0 + 1 < nX - 1) ? 1.f : 0.f;
    m.z = (rin && gc0 + 2 > 0 && gc0 + 2 < nX - 1) ? 1.f : 0.f;
    m.w = (rin && gc0 + 3 > 0 && gc0 + 3 < nX - 1) ? 1.f : 0.f;
}

__device__ __forceinline__ void step_one(const float* __restrict__ bc,
                                         float* __restrict__ bn,
                                         int a, const float4& m, float4& c,
                                         float gamma) {
    const float4 u4 = *reinterpret_cast<const float4*>(bc + a - PAD);
    const float4 d4 = *reinterpret_cast<const float4*>(bc + a + PAD);
    const float lf = bc[a - 1];
    const float rt = bc[a + 4];
    float4 o;
    o.x = m.x * (c.x + gamma * (u4.x + d4.x + lf  + c.y - 4.f * c.x));
    o.y = m.y * (c.y + gamma * (u4.y + d4.y + c.x + c.z - 4.f * c.y));
    o.z = m.z * (c.z + gamma * (u4.z + d4.z + c.y + c.w - 4.f * c.z));
    o.w = m.w * (c.w + gamma * (u4.w + d4.w + c.z + rt  - 4.f * c.w));
    *reinterpret_cast<float4*>(bn + a) = o;
    c = o;   // this step's output is next step's center
}

#define BAR() do { \
    asm volatile("s_waitcnt lgkmcnt(0)" ::: "memory"); \
    __builtin_amdgcn_s_barrier(); \
    __builtin_amdgcn_sched_barrier(0); \
} while (0)

__global__ __launch_bounds__(TPB)
void heat_fused(const float* __restrict__ src,       // u0 (first) or frame t_base
                float* __restrict__ out,             // full output base
                int t_base, int k, int nX, int first,
                int time_steps,
                const float* __restrict__ alpha_p,
                const int* __restrict__ T_p) {
    __shared__ float buf[2][REG * PAD];

    const int tid = threadIdx.x;
    const int gb  = nX / CORE;                 // 16
    const int bx  = blockIdx.x % gb;
    const int by  = blockIdx.x / gb;
    const int o_r = by * CORE - HALO;
    const int o_c = bx * CORE - HALO;
    const size_t n0 = (size_t)nX * nX;

    const float alpha = *alpha_p;
    const float Tf    = (float)(*T_p);
    const float dx    = 6.0f / (float)(nX - 1);
    const float dt    = Tf / (float)(time_steps - 1);
    const float gamma = alpha * dt / (dx * dx);

    // ---- load 96x96 tile (strict interior mask: boundaries/OOD -> 0).
    // For first==1 this also materializes reference frame 0 from u0.
    for (int idx = tid; idx < REG * PAD; idx += TPB) {
        const int r = idx / PAD, c = idx % PAD;
        const int gr = o_r + r, gc = o_c + c;
        float v = 0.f;
        if (c < REG && gr > 0 && gr < nX - 1 && gc > 0 && gc < nX - 1)
            v = src[(size_t)gr * nX + gc];
        buf[0][idx] = v;
        if (first && r >= HALO && r < HALO + CORE && c >= HALO && c < HALO + CORE)
            out[(size_t)gr * nX + gc] = v;           // frame 0
    }
    BAR();

    if (tid < NCT) {
        // ================= compute role (waves 0-11) =================
        int a0, a1, a2 = PAD;
        float4 m0, m1, m2 = make_float4(0.f, 0.f, 0.f, 0.f);
        slot_init(tid,       o_r, o_c, nX, a0, m0);
        slot_init(tid + NCT, o_r, o_c, nX, a1, m1);
        const bool has2 = (tid + 2 * NCT) < NIT;
        if (has2) slot_init(tid + 2 * NCT, o_r, o_c, nX, a2, m2);

        float4 c0 = *reinterpret_cast<const float4*>(&buf[0][a0]);
        float4 c1 = *reinterpret_cast<const float4*>(&buf[0][a1]);
        float4 c2 = make_float4(0.f, 0.f, 0.f, 0.f);
        if (has2) c2 = *reinterpret_cast<const float4*>(&buf[0][a2]);

        for (int s = 0; s < k; ++s) {
            const float* __restrict__ bc = buf[s & 1];
            float*       __restrict__ bn = buf[(s & 1) ^ 1];
            step_one(bc, bn, a0, m0, c0, gamma);
            step_one(bc, bn, a1, m1, c1, gamma);
            if (has2) step_one(bc, bn, a2, m2, c2, gamma);
            BAR();
        }
    } else {
        // ================= writer role (waves 12-15) =================
        const int wid = tid - NCT;                 // 0..255
        int wa[4]; size_t wo[4];
        #pragma unroll
        for (int j = 0; j < 4; ++j) {
            const int idx = wid + 256 * j;         // 0..1023 core quads
            const int r = HALO + (idx >> 4);
            const int q = (HALO / 4) + (idx & 15);
            wa[j] = r * PAD + 4 * q;
            wo[j] = (size_t)(o_r + r) * nX + (o_c + 4 * q);
        }
        for (int s = 0; s < k; ++s) {
            if (s >= 1) {
                const float* __restrict__ b = buf[s & 1];   // frame t_base+s
                float* of = out + (size_t)(t_base + s) * n0;
                #pragma unroll
                for (int j = 0; j < 4; ++j)
                    *reinterpret_cast<float4*>(of + wo[j]) =
                        *reinterpret_cast<const float4*>(b + wa[j]);
            }
            BAR();
        }
        // final frame t_base+k sits in buf[k&1]
        const float* __restrict__ b = buf[k & 1];
        float* of = out + (size_t)(t_base + k) * n0;
        #pragma unroll
        for (int j = 0; j < 4; ++j)
            *reinterpret_cast<float4*>(of + wo[j]) =
                *reinterpret_cast<const float4*>(b + wa[j]);
    }
}

extern "C" void kernel_launch(void* const* d_in, const int* in_sizes, int n_in,
                              void* d_out, int out_size, void* d_ws, size_t ws_size,
                              hipStream_t stream) {
    const float* u0      = (const float*)d_in[0];
    const float* alpha_p = (const float*)d_in[1];
    const int*   T_p     = (const int*)d_in[2];

    const int n0 = in_sizes[0];                   // nX*nX
    const int nX = (int)(sqrtf((float)n0) + 0.5f);
    const int ts = out_size / n0;                 // time_steps

    float* out = (float*)d_out;
    const int gb = nX / CORE;                     // 16
    const int nblocks = gb * gb;                  // 256

    for (int t = 0; t < ts - 1; t += HALO) {
        const int k = min(HALO, ts - 1 - t);
        const float* src = (t == 0) ? u0 : out + (size_t)t * n0;
        heat_fused<<<nblocks, TPB, 0, stream>>>(src, out, t, k, nX,
                                                (t == 0) ? 1 : 0, ts,
                                                alpha_p, T_p);
    }
}

// Round 8
// 281.933 us; speedup vs baseline: 1.4082x; 1.2516x over previous
//
#include <hip/hip_runtime.h>
#include <math.h>

// Heat equation, temporally blocked, K=16 steps/launch, 16 dispatches.
// Round 7: revert to round-4 geometry (best: 330 us) and add
//  (a) shrinking active window: at step s only tile rows/cols [s+1, 95-s)
//      can still influence stored output; each slot precomputes its margin
//      and retires when s > margin  (-29% LDS/VALU work),
//  (b) float4-vectorized tile load with fully-interior fast path.
// Geometry: 64x64 core + 16 halo -> 96x96 LDS tile, stride 96, double
// buffered (73.7 KB), 1024 threads, inline register->global frame stores,
// barriers drain lgkmcnt only (stores stay in flight).

#define CORE 64
#define HALO 16
#define REG  96            // CORE + 2*HALO
#define TPB  1024
#define NQ   24            // float4 quads per tile row
#define NIT  (94 * NQ)     // 2256 interior quads per step

__global__ __launch_bounds__(256)
void heat_init(const float* __restrict__ u0, float* __restrict__ out, int nX) {
    const int row = blockIdx.x;
    const int j   = threadIdx.x;
    const int nq  = nX >> 2;
    float4* dst = reinterpret_cast<float4*>(out + (size_t)row * nX);
    if (row == 0 || row == nX - 1) {
        dst[j] = make_float4(0.f, 0.f, 0.f, 0.f);
        return;
    }
    const float4* src = reinterpret_cast<const float4*>(u0 + (size_t)row * nX);
    float4 v = src[j];
    if (j == 0)      v.x = 0.f;
    if (j == nq - 1) v.w = 0.f;
    dst[j] = v;
}

__device__ __forceinline__ void slot_init(int it, int o_r, int o_c, int nX,
                                          int& a, int& off, bool& st, float4& m,
                                          int& margin) {
    const int r = 1 + it / NQ;
    const int q = it % NQ;
    a = r * REG + 4 * q;
    const int gr  = o_r + r;
    const int gc0 = o_c + 4 * q;
    off = gr * nX + gc0;
    st  = (r >= HALO && r < HALO + CORE && q >= HALO / 4 && q < (REG - HALO) / 4);
    const bool rin = (gr > 0 && gr < nX - 1);
    m.x = (rin && gc0     > 0 && gc0     < nX - 1) ? 1.f : 0.f;
    m.y = (rin && gc0 + 1 > 0 && gc0 + 1 < nX - 1) ? 1.f : 0.f;
    m.z = (rin && gc0 + 2 > 0 && gc0 + 2 < nX - 1) ? 1.f : 0.f;
    m.w = (rin && gc0 + 3 > 0 && gc0 + 3 < nX - 1) ? 1.f : 0.f;
    // slot can still influence stored output while s <= margin
    margin = min(min(r - 1, 94 - r), min(4 * q + 2, 94 - 4 * q));
}

__device__ __forceinline__ void step_one(const float* __restrict__ bc,
                                         float* __restrict__ bn,
                                         float* __restrict__ of,
                                         int a, int off, bool st,
                                         const float4& m, float4& c, float gamma) {
    const float4 u4 = *reinterpret_cast<const float4*>(bc + a - REG);
    const float4 d4 = *reinterpret_cast<const float4*>(bc + a + REG);
    const float lf = bc[a - 1];
    const float rt = bc[a + 4];
    float4 o;
    o.x = m.x * (c.x + gamma * (u4.x + d4.x + lf  + c.y - 4.f * c.x));
    o.y = m.y * (c.y + gamma * (u4.y + d4.y + c.x + c.z - 4.f * c.y));
    o.z = m.z * (c.z + gamma * (u4.z + d4.z + c.y + c.w - 4.f * c.z));
    o.w = m.w * (c.w + gamma * (u4.w + d4.w + c.z + rt  - 4.f * c.w));
    *reinterpret_cast<float4*>(bn + a) = o;
    if (st) *reinterpret_cast<float4*>(of + off) = o;
    c = o;   // this step's output is next step's center
}

#define BAR() do { \
    asm volatile("s_waitcnt lgkmcnt(0)" ::: "memory"); \
    __builtin_amdgcn_s_barrier(); \
    __builtin_amdgcn_sched_barrier(0); \
} while (0)

__global__ __launch_bounds__(TPB)
void heat_fused(const float* __restrict__ src,       // frame t_base
                float* __restrict__ out,             // full output base
                int t_base, int k, int nX, int time_steps,
                const float* __restrict__ alpha_p,
                const int* __restrict__ T_p) {
    __shared__ float buf[2][REG * REG];

    const int tid = threadIdx.x;
    const int gb  = nX / CORE;                 // 16
    const int bx  = blockIdx.x % gb;
    const int by  = blockIdx.x / gb;
    const int o_r = by * CORE - HALO;
    const int o_c = bx * CORE - HALO;
    const size_t n0 = (size_t)nX * nX;

    const float alpha = *alpha_p;
    const float Tf    = (float)(*T_p);
    const float dx    = 6.0f / (float)(nX - 1);
    const float dt    = Tf / (float)(time_steps - 1);
    const float gamma = alpha * dt / (dx * dx);

    // ---- load 96x96 tile of frame t_base, float4-vectorized ----
    for (int qi = tid; qi < REG * NQ; qi += TPB) {
        const int r = qi / NQ, q = qi % NQ;
        const int gr = o_r + r, gc0 = o_c + 4 * q;
        float4 v = make_float4(0.f, 0.f, 0.f, 0.f);
        if (gr >= 0 && gr < nX) {
            const float* sp = src + (size_t)gr * nX + gc0;
            if (gc0 >= 0 && gc0 + 3 < nX) {
                v = *reinterpret_cast<const float4*>(sp);   // fast path
            } else {
                if (gc0     >= 0 && gc0     < nX) v.x = sp[0];
                if (gc0 + 1 >= 0 && gc0 + 1 < nX) v.y = sp[1];
                if (gc0 + 2 >= 0 && gc0 + 2 < nX) v.z = sp[2];
                if (gc0 + 3 >= 0 && gc0 + 3 < nX) v.w = sp[3];
            }
        }
        *reinterpret_cast<float4*>(&buf[0][r * REG + 4 * q]) = v;
    }
    BAR();

    // ---- per-slot loop invariants ----
    int a0, a1, a2 = REG, off0, off1, off2 = 0, mg0, mg1, mg2 = -1;
    bool st0, st1, st2 = false;
    float4 m0, m1, m2 = make_float4(0.f, 0.f, 0.f, 0.f);
    slot_init(tid,       o_r, o_c, nX, a0, off0, st0, m0, mg0);
    slot_init(tid + TPB, o_r, o_c, nX, a1, off1, st1, m1, mg1);
    const bool has2 = (tid + 2 * TPB) < NIT;
    if (has2) slot_init(tid + 2 * TPB, o_r, o_c, nX, a2, off2, st2, m2, mg2);

    float4 c0 = *reinterpret_cast<const float4*>(&buf[0][a0]);
    float4 c1 = *reinterpret_cast<const float4*>(&buf[0][a1]);
    float4 c2 = make_float4(0.f, 0.f, 0.f, 0.f);
    if (has2) c2 = *reinterpret_cast<const float4*>(&buf[0][a2]);

    for (int s = 0; s < k; ++s) {
        const float* __restrict__ bc = buf[s & 1];
        float*       __restrict__ bn = buf[(s & 1) ^ 1];
        float* of = out + (size_t)(t_base + s + 1) * n0;

        if (s <= mg0) step_one(bc, bn, of, a0, off0, st0, m0, c0, gamma);
        if (s <= mg1) step_one(bc, bn, of, a1, off1, st1, m1, c1, gamma);
        if (s <= mg2) step_one(bc, bn, of, a2, off2, st2, m2, c2, gamma);

        // LDS-only drain; global stores remain in flight across the barrier
        BAR();
    }
}

extern "C" void kernel_launch(void* const* d_in, const int* in_sizes, int n_in,
                              void* d_out, int out_size, void* d_ws, size_t ws_size,
                              hipStream_t stream) {
    const float* u0      = (const float*)d_in[0];
    const float* alpha_p = (const float*)d_in[1];
    const int*   T_p     = (const int*)d_in[2];

    const int n0 = in_sizes[0];                   // nX*nX
    const int nX = (int)(sqrtf((float)n0) + 0.5f);
    const int ts = out_size / n0;                 // time_steps

    float* out = (float*)d_out;
    const int gb = nX / CORE;                     // 16
    const int nblocks = gb * gb;                  // 256

    heat_init<<<nX, nX / 4, 0, stream>>>(u0, out, nX);

    for (int t = 0; t < ts - 1; t += HALO) {
        const int k = min(HALO, ts - 1 - t);
        heat_fused<<<nblocks, TPB, 0, stream>>>(out + (size_t)t * n0, out,
                                                t, k, nX, ts, alpha_p, T_p);
    }
}